// Round 14
// baseline (273.496 us; speedup 1.0000x reference)
//
#include <hip/hip_runtime.h>
#include <cstdint>
#include <climits>
#include <cstddef>

#define TK 13
#define MAXG 128
#define CAP 192
#define NW 4
#define MCAP 24576
#define MAXCH 160

__device__ __forceinline__ float iou_fn(const float4 pb, const float4 gb){
  float pa = (pb.z - pb.x) * (pb.w - pb.y);
  float ga = (gb.z - gb.x) * (gb.w - gb.y);
  float ltx = fmaxf(pb.x, gb.x), lty = fmaxf(pb.y, gb.y);
  float rbx = fminf(pb.z, gb.z), rby = fminf(pb.w, gb.w);
  float w = fmaxf(rbx - ltx, 0.0f), h = fmaxf(rby - lty, 0.0f);
  float inter = w * h;
  float uni = pa + ga - inter;
  return inter / fmaxf(uni, 1e-6f);
}

__device__ __forceinline__ float sigmoid_f(float x){ return 1.0f / (1.0f + expf(-x)); }

// Same expression order as R0-R13 (passed absmax 0) — do not alter.
__device__ __forceinline__ float cost_full(float iou, float s, float dist){
  float sig = sigmoid_f(s);
  float iouc = -logf(iou + 1e-7f) * 3.0f;
  float scale = iou - sig;
  float bce = fmaxf(s, 0.0f) + log1pf(expf(-fabsf(s))) - s * iou;
  float cls = bce * scale * scale;
  float soft = powf(10.0f, dist - 3.0f);
  return cls + iouc + soft;
}

__device__ __forceinline__ void bfly_max_u64(unsigned long long &v, int &l){
  #pragma unroll
  for (int off = 32; off >= 1; off >>= 1){
    unsigned long long ov = __shfl_xor(v, off);
    int ol = __shfl_xor(l, off);
    if (ov > v){ v = ov; l = ol; }
  }
}

// wave-level: find 13th-largest of cnt entries in buf; compact top-13 to
// buf[0..12]; return 13th key (0 if fewer than 13 nonzero). Keys unique.
__device__ __forceinline__ unsigned long long squeeze13(unsigned long long* buf, int& cnt, int lane){
  unsigned long long e0 = (lane < cnt) ? buf[lane] : 0ull;
  unsigned long long e1 = (lane + 64 < cnt) ? buf[lane + 64] : 0ull;
  unsigned long long e2 = (lane + 128 < cnt) ? buf[lane + 128] : 0ull;
  if (e0 < e2){ unsigned long long t = e0; e0 = e2; e2 = t; }
  if (e0 < e1){ unsigned long long t = e0; e0 = e1; e1 = t; }
  if (e1 < e2){ unsigned long long t = e1; e1 = e2; e2 = t; }
  unsigned long long T = 0;
  for (int r = 0; r < TK; ++r){
    unsigned long long m = e0; int l = lane;
    bfly_max_u64(m, l);
    if (lane == 0) buf[r] = m;
    T = m;
    if (lane == l){ e0 = e1; e1 = e2; e2 = 0ull; }
  }
  cnt = TK;
  return T;
}

// Kernel A: valid bitmask + acc init + mcnt zero + per-chunk AABBs.
__global__ __launch_bounds__(256) void k_valid(
    const float4* __restrict__ priors, const float4* __restrict__ pred_bboxes,
    const float4* __restrict__ gtb, const float* __restrict__ pad,
    unsigned long long* __restrict__ vmask, unsigned int* __restrict__ acc,
    unsigned int* __restrict__ mcnt,
    float4* __restrict__ predAB, float4* __restrict__ prAB, float* __restrict__ strC,
    int P, int G, int nCh)
{
  int b = blockIdx.y;
  int p = blockIdx.x * 256 + threadIdx.x;
  if (b == 0 && p == 0) *mcnt = 0u;
  __shared__ float4 sg[MAXG];
  __shared__ float sp[MAXG];
  for (int i = threadIdx.x; i < G; i += 256){ sg[i] = gtb[b*G + i]; sp[i] = pad[b*G + i]; }
  __syncthreads();
  int lane = threadIdx.x & 63;
  int ch = p >> 6;
  bool inb = p < P;
  float4 pr = inb ? priors[p] : make_float4(0,0,0,0);
  float4 pb = inb ? pred_bboxes[(size_t)b*P + p] : make_float4(0,0,0,0);
  bool v = false;
  if (inb){
    #pragma unroll 4
    for (int g = 0; g < G; ++g){
      float4 gb = sg[g];
      bool ig = (pr.x > gb.x) && (pr.y > gb.y) && (gb.z > pr.x) && (gb.w > pr.y);
      v = v || (ig && sp[g] > 0.5f);
    }
    acc[(size_t)b * P + p] = 0u;
  }
  unsigned long long m = __ballot(v);
  if (lane == 0 && ch < nCh) vmask[(size_t)b * nCh + ch] = m;
  float inf = __builtin_inff();
  float x1 = inb ? pb.x : inf,  y1 = inb ? pb.y : inf;
  float x2 = inb ? pb.z : -inf, y2 = inb ? pb.w : -inf;
  float px1 = inb ? pr.x : inf,  py1 = inb ? pr.y : inf;
  float px2 = inb ? pr.x : -inf, py2 = inb ? pr.y : -inf;
  #pragma unroll
  for (int off = 32; off >= 1; off >>= 1){
    x1 = fminf(x1, __shfl_xor(x1, off));  y1 = fminf(y1, __shfl_xor(y1, off));
    x2 = fmaxf(x2, __shfl_xor(x2, off));  y2 = fmaxf(y2, __shfl_xor(y2, off));
    px1 = fminf(px1, __shfl_xor(px1, off)); py1 = fminf(py1, __shfl_xor(py1, off));
    px2 = fmaxf(px2, __shfl_xor(px2, off)); py2 = fmaxf(py2, __shfl_xor(py2, off));
  }
  if (lane == 0 && ch < nCh){
    predAB[(size_t)b * nCh + ch] = make_float4(x1, y1, x2, y2);
    if (b == 0){ prAB[ch] = make_float4(px1, py1, px2, py2); strC[ch] = pr.z; }
  }
}

// Kernel B: one 4-wave block per (b,g). Per-chunk geo (geoI/geoM/drr) and
// vmask words precomputed into LDS at block start — the per-iteration skip
// test is one LDS read + a float compare. Same selection logic as R13.
__global__ __launch_bounds__(256) void k_scan(
    const float4* __restrict__ pred_bboxes, const float* __restrict__ pred_scores,
    const float4* __restrict__ priors, const int* __restrict__ gt_labels,
    const float4* __restrict__ gtbb, const float* __restrict__ pad,
    const unsigned long long* __restrict__ vmask,
    const float4* __restrict__ predAB, const float4* __restrict__ prAB,
    const float* __restrict__ strC,
    unsigned int* __restrict__ acc, unsigned int* __restrict__ mcnt,
    unsigned int* __restrict__ mlist,
    int P, int G, int C, int nCh)
{
  int bg = blockIdx.x;
  if (pad[bg] <= 0.5f) return;
  int b = bg / G;
  int g = bg - b * G;
  int tid = threadIdx.x;
  int lane = tid & 63;
  int wv = tid >> 6;
  float4 gb = gtbb[bg];
  int lbl = gt_labels[bg];
  float gcx = (gb.x + gb.z) * 0.5f, gcy = (gb.y + gb.w) * 0.5f;
  size_t bP = (size_t)b * P;
  const unsigned long long* vmb = vmask + (size_t)b * nCh;
  const float4* pAB = predAB + (size_t)b * nCh;
  const unsigned B1E8 = __float_as_uint(1e8f);

  __shared__ unsigned long long bufM[NW*CAP], bufC[NW*CAP], bufI[NW*CAP];
  __shared__ uint2 sgeo[MAXCH];               // {flags: bit0 geoI, bit1 geoM; drr bits}
  __shared__ unsigned long long svm[MAXCH];   // per-chunk valid bitmask
  __shared__ unsigned int shwC, shwM, shwI;
  if (tid == 0){ shwC = 0xFFFFFFFFu; shwM = 0u; shwI = 0u; }
  // cooperative per-chunk geo precompute (bit-identical expressions to R13)
  for (int ch = tid; ch < nCh; ch += 256){
    float4 pA = pAB[ch];
    float4 rA = prAB[ch];
    float strc = strC[ch];
    bool geoI = !(pA.x < gb.z && pA.z > gb.x && pA.y < gb.w && pA.w > gb.y);
    bool geoM = !(rA.z > gb.x && rA.x < gb.z && rA.w > gb.y && rA.y < gb.w);
    float dxr = fmaxf(0.0f, fmaxf(rA.x - gcx, gcx - rA.z));
    float dyr = fmaxf(0.0f, fmaxf(rA.y - gcy, gcy - rA.w));
    float drr = sqrtf(dxr*dxr + dyr*dyr) / strc;
    sgeo[ch] = make_uint2((geoI ? 1u : 0u) | (geoM ? 2u : 0u), __float_as_uint(drr));
    svm[ch] = vmb[ch];
  }
  __syncthreads();
  unsigned long long* bM = bufM + wv*CAP;
  unsigned long long* bC = bufC + wv*CAP;
  unsigned long long* bI = bufI + wv*CAP;

  int cntM = 0, cntC = 0, cntI = 0;
  int zM = 0, zC = 0;
  unsigned long long Tm = 0ull, Tc = 0ull;
  unsigned long long Ti = 0x00000000FFFFFFFFull;    // prune iou==0 always
  unsigned cbits = 0xFFFFFFFFu, mBbits = 0u, iBb = 0u;
  float thr = 1e30f, mB = 0.0f;
  unsigned long long laneLT = (1ull << lane) - 1ull;

  for (int c = wv; c < nCh; c += NW){
    { unsigned sC = shwC; if (sC < cbits){ cbits = sC;
        thr = 3.0f + log10f(__uint_as_float(cbits) * 1.00002f + 1e-6f); } }
    { unsigned sM = shwM; if (sM > mBbits){ mBbits = sM; mB = __uint_as_float(sM); } }
    { unsigned sI = shwI; if (sI > iBb) iBb = sI; }
    uint2 ge = sgeo[c];
    bool geoI = (ge.x & 1u) != 0u;
    bool geoM = (ge.x & 2u) != 0u;
    float drr = __uint_as_float(ge.y);
    bool poolM = (zM >= TK) || (mBbits > 0u);
    bool poolC = (zC >= TK) || (cbits < B1E8);
    bool skipMt = geoM && poolM;
    bool skipCt = (drr > thr) && poolC;
    if (!(geoI && skipMt && skipCt)){
      int p = c * 64 + lane;
      bool inb = p < P;
      float4 pb = inb ? pred_bboxes[bP + p] : make_float4(0,0,0,0);
      float iou = iou_fn(pb, gb);
      unsigned long long keyI = ((unsigned long long)__float_as_uint(iou) << 32) | (unsigned)p;
      bool candI = inb && (keyI > Ti) && !((unsigned)(keyI >> 32) < iBb);
      if (cntI > CAP - 64){
        Ti = squeeze13(bI, cntI, lane);
        unsigned ib = (unsigned)(Ti >> 32);
        if (ib > iBb) iBb = ib;
        if (lane == 0 && ib) atomicMax(&shwI, ib);
        candI = candI && (keyI > Ti) && !((unsigned)(keyI >> 32) < iBb);
      }
      { unsigned long long mk = __ballot(candI);
        if (mk){ int off = cntI + __popcll(mk & laneLT); if (candI) bI[off] = keyI; cntI += __popcll(mk); } }
      if (!(skipMt && skipCt)){
        // ---- full path (identical to R13 body) ----
        float4 pr = inb ? priors[p] : make_float4(0,0,0,0);
        bool vb = inb && (((svm[c] >> lane) & 1ull) != 0ull);
        bool ig = inb && (pr.x > gb.x) && (pr.y > gb.y) && (gb.z > pr.x) && (gb.w > pr.y);
        bool pos = ig && (iou > 0.0f);
        float i2 = iou * iou;
        float bnd = (i2 * i2) * i2 * 1.000002f;     // >= sigmoid*powf(iou,6)
        bool needm = pos && !(bnd < mB);
        float dist = 0.0f; bool needc = false;
        if (vb){
          float dx = pr.x - gcx, dy = pr.y - gcy;
          dist = sqrtf(dx*dx + dy*dy) / pr.z;
          needc = !(dist > thr);
        }
        float sc = 0.0f;
        if (needm || needc) sc = pred_scores[(bP + p) * C + lbl];
        unsigned long long keyM = 0;
        if (__ballot(needm)){
          float met = sigmoid_f(sc) * powf(iou, 6.0f);
          if (needm)
            keyM = ((unsigned long long)__float_as_uint(met) << 32)
                 | (unsigned)~(unsigned)((p << 1) | 1);
        }
        if (zM < TK && inb && !pos)                 // zero-metric fill pool
          keyM = (unsigned long long)(unsigned)~(unsigned)((p << 1) | (ig ? 1 : 0));
        bool candM = (keyM != 0ull) && (keyM > Tm) && !((unsigned)(keyM >> 32) < mBbits);
        unsigned long long keyC = 0;
        if (zC < TK && inb && !vb)                  // invalid-cost fill pool
          keyC = ~(((unsigned long long)__float_as_uint(1e8f) << 32) | (unsigned)p);
        if (__ballot(needc)){
          float cst = cost_full(iou, sc, dist);
          if (needc)
            keyC = ~(((unsigned long long)__float_as_uint(cst) << 32) | (unsigned)p);
        }
        bool candC = (keyC != 0ull) && (keyC > Tc) && !((unsigned)((~keyC) >> 32) > cbits);
        if (cntM > CAP - 64){
          Tm = squeeze13(bM, cntM, lane);
          unsigned tb = (unsigned)(Tm >> 32);
          if (tb > mBbits){ mBbits = tb; mB = __uint_as_float(tb); }
          if (lane == 0 && tb) atomicMax(&shwM, tb);
          candM = candM && (keyM > Tm) && !((unsigned)(keyM >> 32) < mBbits);
        }
        { unsigned long long mk = __ballot(candM);
          if (mk){
            int off = cntM + __popcll(mk & laneLT);
            if (candM) bM[off] = keyM;
            cntM += __popcll(mk);
            unsigned long long zk = __ballot(candM && !pos);
            zM += __popcll(zk);
          } }
        if (cntC > CAP - 64){
          Tc = squeeze13(bC, cntC, lane);
          unsigned cb = (unsigned)((~Tc) >> 32);
          if (cb < cbits){ cbits = cb;
            thr = 3.0f + log10f(__uint_as_float(cbits) * 1.00002f + 1e-6f); }
          if (lane == 0) atomicMin(&shwC, cb);
          candC = candC && (keyC > Tc) && !((unsigned)((~keyC) >> 32) > cbits);
        }
        { unsigned long long mk = __ballot(candC);
          if (mk){
            int off = cntC + __popcll(mk & laneLT);
            if (candC) bC[off] = keyC;
            cntC += __popcll(mk);
            unsigned long long zk = __ballot(candC && !vb);
            zC += __popcll(zk);
          } }
      }
    }
  }

  squeeze13(bI, cntI, lane);
  squeeze13(bM, cntM, lane);
  squeeze13(bC, cntC, lane);
  __syncthreads();
  if (wv != 0) return;

  // ---- wave0: global top-13 from 4x13 survivors per criterion ----
  int w13 = lane / TK, r13 = lane - w13 * TK;
  int kd;
  { // iou -> dynamic_k (desc-order sum, fp-exact vs ref)
    unsigned long long e = (lane < NW*TK) ? bufI[w13*CAP + r13] : 0ull;
    float ksum = 0.0f;
    for (int r = 0; r < TK; ++r){
      unsigned long long m = e; int l = lane;
      bfly_max_u64(m, l);
      ksum += __uint_as_float((unsigned)(m >> 32));
      if (lane == l) e = 0ull;
    }
    kd = (int)ksum; if (kd < 1) kd = 1;
  }
  { // metric -> fg marks
    unsigned long long e = (lane < NW*TK) ? bufM[w13*CAP + r13] : 0ull;
    for (int r = 0; r < TK; ++r){
      unsigned long long m = e; int l = lane;
      bfly_max_u64(m, l);
      if (m == 0ull) break;
      if (lane == 0){
        unsigned ix = ~(unsigned)(m & 0xFFFFFFFFull);
        if (ix & 1u) atomicOr(&acc[bP + (ix >> 1)], 2u);
      }
      if (lane == l) e = 0ull;
    }
  }
  { // cost -> first kd selections; multi-detect on 1->2 transition
    unsigned long long e = (lane < NW*TK) ? bufC[w13*CAP + r13] : 0ull;
    for (int r = 0; r < kd; ++r){
      unsigned long long m = e; int l = lane;
      bfly_max_u64(m, l);
      if (m == 0ull) break;
      if (lane == 0){
        unsigned pp = (unsigned)((~m) & 0xFFFFFFFFull);
        unsigned old = atomicAdd(&acc[bP + pp], (1u << 17) | ((unsigned)g << 2));
        if ((old >> 17) == 1u){
          unsigned mi = atomicAdd(mcnt, 1u);
          if (mi < MCAP) mlist[mi] = (unsigned)(bP + pp);
        }
      }
      if (lane == l) e = 0ull;
    }
  }
}

// Kernel C: uniform decode; multi priors get a placeholder (k_multi overwrites).
__global__ __launch_bounds__(256) void k_final(
    const float4* __restrict__ pred_bboxes, const int* __restrict__ gt_labels,
    const float4* __restrict__ gtb, const unsigned int* __restrict__ acc,
    float* __restrict__ out, int B, int P, int G)
{
  int b = blockIdx.y;
  int p = blockIdx.x * 256 + threadIdx.x;
  __shared__ float4 sg[MAXG];
  __shared__ int sl[MAXG];
  for (int i = threadIdx.x; i < G; i += 256){
    sg[i] = gtb[b*G + i]; sl[i] = gt_labels[b*G + i];
  }
  __syncthreads();
  if (p >= P) return;
  size_t o = (size_t)b * P + p;
  unsigned int w = acc[o];
  int cnt = (int)(w >> 17);
  bool fg = cnt > 0;
  int mg = (cnt == 1) ? (int)((w >> 2) & 0x7FFFu) : 0;  // cnt>1 -> placeholder
  float4 pb = pred_bboxes[o];
  size_t BP = (size_t)B * P;
  out[o] = fg ? (float)sl[mg] : 80.0f;
  out[BP + o] = 1.0f;
  float4 ob = fg ? sg[mg] : make_float4(0.f, 0.f, 0.f, 0.f);
  ((float4*)(out + 2*BP))[o] = ob;
  out[6*BP + o] = fg ? iou_fn(pb, sg[mg]) : 0.0f;
  out[7*BP + o] = ((w >> 1) & 1u) ? 1.0f : 0.0f;
}

// Kernel D: one wave per multi-matched prior; exact argmin cost over all g.
__global__ __launch_bounds__(256) void k_multi(
    const float4* __restrict__ pred_bboxes, const float* __restrict__ pred_scores,
    const float4* __restrict__ priors, const int* __restrict__ gt_labels,
    const float4* __restrict__ gtb, const unsigned long long* __restrict__ vmask,
    const unsigned int* __restrict__ mcnt, const unsigned int* __restrict__ mlist,
    float* __restrict__ out, int B, int P, int G, int C, int nCh)
{
  unsigned n = *mcnt; if (n > MCAP) n = MCAP;
  int lane = threadIdx.x & 63;
  int wid = (blockIdx.x * (blockDim.x >> 6)) + (threadIdx.x >> 6);
  int nw = gridDim.x * (blockDim.x >> 6);
  size_t BP = (size_t)B * P;
  for (unsigned i = wid; i < n; i += nw){
    unsigned o = mlist[i];
    int b = o / P;
    int p = o - b * P;
    float4 pb = pred_bboxes[o];
    bool vld = (vmask[(size_t)b * nCh + (p >> 6)] >> (p & 63)) & 1ull;
    int mg = 0;
    if (vld){
      float4 pr = priors[p];
      const float* srow = pred_scores + (size_t)o * C;
      unsigned long long best = 0xFFFFFFFFFFFFFFFFull;
      for (int g0 = lane; g0 < G; g0 += 64){
        float4 gbx = gtb[b*G + g0];
        float iou = iou_fn(pb, gbx);
        float s = srow[gt_labels[b*G + g0]];
        float gcx = (gbx.x + gbx.z) * 0.5f, gcy = (gbx.y + gbx.w) * 0.5f;
        float dx = pr.x - gcx, dy = pr.y - gcy;
        float dist = sqrtf(dx*dx + dy*dy) / pr.z;
        float cc = cost_full(iou, s, dist);
        unsigned long long k = ((unsigned long long)__float_as_uint(cc) << 32) | (unsigned)g0;
        if (k < best) best = k;
      }
      #pragma unroll
      for (int off = 32; off >= 1; off >>= 1){
        unsigned long long ov = __shfl_xor(best, off);
        if (ov < best) best = ov;
      }
      mg = (int)(best & 0xFFFFFFFFull);
    }
    if (lane == 0){
      float4 gbx = gtb[b*G + mg];
      out[o] = (float)gt_labels[b*G + mg];
      ((float4*)(out + 2*BP))[o] = gbx;
      out[6*BP + o] = iou_fn(pb, gbx);
    }
  }
}

extern "C" void kernel_launch(void* const* d_in, const int* in_sizes, int n_in,
                              void* d_out, int out_size, void* d_ws, size_t ws_size,
                              hipStream_t stream)
{
  const float4* pred_bboxes = (const float4*)d_in[0];
  const float*  pred_scores = (const float*)d_in[1];
  const float4* priors      = (const float4*)d_in[2];
  const int*    gt_labels   = (const int*)d_in[3];
  const float4* gt_bboxes   = (const float4*)d_in[4];
  const float*  pad         = (const float*)d_in[5];
  int P = in_sizes[2] / 4;                 // 8400
  int B = in_sizes[0] / (P * 4);           // 16
  int C = in_sizes[1] / (B * P);           // 80
  int G = in_sizes[4] / (B * 4);           // 100
  int BG = B * G;
  int nCh = (P + 63) >> 6;                 // 132 (must be <= MAXCH)

  uint8_t* ws = (uint8_t*)d_ws;
  size_t off = 0;
  unsigned long long* vmask = (unsigned long long*)(ws + off); off += (size_t)B * nCh * 8;
  unsigned int* acc = (unsigned int*)(ws + off);               off += (size_t)B * P * 4;
  off = (off + 15) & ~(size_t)15;
  unsigned int* mcnt = (unsigned int*)(ws + off);              off += 16;
  unsigned int* mlist = (unsigned int*)(ws + off);             off += (size_t)MCAP * 4;
  off = (off + 15) & ~(size_t)15;
  float4* predAB = (float4*)(ws + off);                        off += (size_t)B * nCh * 16;
  float4* prAB = (float4*)(ws + off);                          off += (size_t)nCh * 16;
  float* strC = (float*)(ws + off);                            off += (size_t)nCh * 4;
  float* out = (float*)d_out;

  dim3 gridA((P + 255) / 256, B);
  k_valid<<<gridA, 256, 0, stream>>>(priors, pred_bboxes, gt_bboxes, pad,
                                     vmask, acc, mcnt, predAB, prAB, strC, P, G, nCh);
  k_scan<<<BG, NW*64, 0, stream>>>(pred_bboxes, pred_scores, priors, gt_labels,
                                   gt_bboxes, pad, vmask, predAB, prAB, strC,
                                   acc, mcnt, mlist, P, G, C, nCh);
  k_final<<<gridA, 256, 0, stream>>>(pred_bboxes, gt_labels, gt_bboxes, acc, out, B, P, G);
  k_multi<<<64, 256, 0, stream>>>(pred_bboxes, pred_scores, priors, gt_labels, gt_bboxes,
                                  vmask, mcnt, mlist, out, B, P, G, C, nCh);
}

// Round 15
// 262.551 us; speedup vs baseline: 1.0417x; 1.0417x over previous
//
#include <hip/hip_runtime.h>
#include <cstdint>
#include <climits>
#include <cstddef>

#define TK 13
#define MAXG 128
#define CAP 192
#define NW 4
#define MCAP 24576
#define MAXCH 160
#define MBX 8

__device__ __forceinline__ float iou_fn(const float4 pb, const float4 gb){
  float pa = (pb.z - pb.x) * (pb.w - pb.y);
  float ga = (gb.z - gb.x) * (gb.w - gb.y);
  float ltx = fmaxf(pb.x, gb.x), lty = fmaxf(pb.y, gb.y);
  float rbx = fminf(pb.z, gb.z), rby = fminf(pb.w, gb.w);
  float w = fmaxf(rbx - ltx, 0.0f), h = fmaxf(rby - lty, 0.0f);
  float inter = w * h;
  float uni = pa + ga - inter;
  return inter / fmaxf(uni, 1e-6f);
}

__device__ __forceinline__ float sigmoid_f(float x){ return 1.0f / (1.0f + expf(-x)); }

// Same expression order as R0-R14 (passed absmax 0) — do not alter.
__device__ __forceinline__ float cost_full(float iou, float s, float dist){
  float sig = sigmoid_f(s);
  float iouc = -logf(iou + 1e-7f) * 3.0f;
  float scale = iou - sig;
  float bce = fmaxf(s, 0.0f) + log1pf(expf(-fabsf(s))) - s * iou;
  float cls = bce * scale * scale;
  float soft = powf(10.0f, dist - 3.0f);
  return cls + iouc + soft;
}

__device__ __forceinline__ void bfly_max_u64(unsigned long long &v, int &l){
  #pragma unroll
  for (int off = 32; off >= 1; off >>= 1){
    unsigned long long ov = __shfl_xor(v, off);
    int ol = __shfl_xor(l, off);
    if (ov > v){ v = ov; l = ol; }
  }
}

// wave-level: find 13th-largest of cnt entries in buf; compact top-13 to
// buf[0..12]; return 13th key (0 if fewer than 13 nonzero). Keys unique.
__device__ __forceinline__ unsigned long long squeeze13(unsigned long long* buf, int& cnt, int lane){
  unsigned long long e0 = (lane < cnt) ? buf[lane] : 0ull;
  unsigned long long e1 = (lane + 64 < cnt) ? buf[lane + 64] : 0ull;
  unsigned long long e2 = (lane + 128 < cnt) ? buf[lane + 128] : 0ull;
  if (e0 < e2){ unsigned long long t = e0; e0 = e2; e2 = t; }
  if (e0 < e1){ unsigned long long t = e0; e0 = e1; e1 = t; }
  if (e1 < e2){ unsigned long long t = e1; e1 = e2; e2 = t; }
  unsigned long long T = 0;
  for (int r = 0; r < TK; ++r){
    unsigned long long m = e0; int l = lane;
    bfly_max_u64(m, l);
    if (lane == 0) buf[r] = m;
    T = m;
    if (lane == l){ e0 = e1; e1 = e2; e2 = 0ull; }
  }
  cnt = TK;
  return T;
}

// Kernel A: valid bitmask + acc init + mcnt zero + per-chunk AABBs.
__global__ __launch_bounds__(256) void k_valid(
    const float4* __restrict__ priors, const float4* __restrict__ pred_bboxes,
    const float4* __restrict__ gtb, const float* __restrict__ pad,
    unsigned long long* __restrict__ vmask, unsigned int* __restrict__ acc,
    unsigned int* __restrict__ mcnt,
    float4* __restrict__ predAB, float4* __restrict__ prAB, float* __restrict__ strC,
    int P, int G, int nCh)
{
  int b = blockIdx.y;
  int p = blockIdx.x * 256 + threadIdx.x;
  if (b == 0 && p == 0) *mcnt = 0u;
  __shared__ float4 sg[MAXG];
  __shared__ float sp[MAXG];
  for (int i = threadIdx.x; i < G; i += 256){ sg[i] = gtb[b*G + i]; sp[i] = pad[b*G + i]; }
  __syncthreads();
  int lane = threadIdx.x & 63;
  int ch = p >> 6;
  bool inb = p < P;
  float4 pr = inb ? priors[p] : make_float4(0,0,0,0);
  float4 pb = inb ? pred_bboxes[(size_t)b*P + p] : make_float4(0,0,0,0);
  bool v = false;
  if (inb){
    #pragma unroll 4
    for (int g = 0; g < G; ++g){
      float4 gb = sg[g];
      bool ig = (pr.x > gb.x) && (pr.y > gb.y) && (gb.z > pr.x) && (gb.w > pr.y);
      v = v || (ig && sp[g] > 0.5f);
    }
    acc[(size_t)b * P + p] = 0u;
  }
  unsigned long long m = __ballot(v);
  if (lane == 0 && ch < nCh) vmask[(size_t)b * nCh + ch] = m;
  float inf = __builtin_inff();
  float x1 = inb ? pb.x : inf,  y1 = inb ? pb.y : inf;
  float x2 = inb ? pb.z : -inf, y2 = inb ? pb.w : -inf;
  float px1 = inb ? pr.x : inf,  py1 = inb ? pr.y : inf;
  float px2 = inb ? pr.x : -inf, py2 = inb ? pr.y : -inf;
  #pragma unroll
  for (int off = 32; off >= 1; off >>= 1){
    x1 = fminf(x1, __shfl_xor(x1, off));  y1 = fminf(y1, __shfl_xor(y1, off));
    x2 = fmaxf(x2, __shfl_xor(x2, off));  y2 = fmaxf(y2, __shfl_xor(y2, off));
    px1 = fminf(px1, __shfl_xor(px1, off)); py1 = fminf(py1, __shfl_xor(py1, off));
    px2 = fmaxf(px2, __shfl_xor(px2, off)); py2 = fmaxf(py2, __shfl_xor(py2, off));
  }
  if (lane == 0 && ch < nCh){
    predAB[(size_t)b * nCh + ch] = make_float4(x1, y1, x2, y2);
    if (b == 0){ prAB[ch] = make_float4(px1, py1, px2, py2); strC[ch] = pr.z; }
  }
}

// Kernel B: one 4-wave block per (b,g). LDS geo precompute (R14) + register
// prefetch of next chunk's pred_bboxes (R13). Same selection logic.
__global__ __launch_bounds__(256) void k_scan(
    const float4* __restrict__ pred_bboxes, const float* __restrict__ pred_scores,
    const float4* __restrict__ priors, const int* __restrict__ gt_labels,
    const float4* __restrict__ gtbb, const float* __restrict__ pad,
    const unsigned long long* __restrict__ vmask,
    const float4* __restrict__ predAB, const float4* __restrict__ prAB,
    const float* __restrict__ strC,
    unsigned int* __restrict__ acc, unsigned int* __restrict__ mcnt,
    unsigned int* __restrict__ mlist,
    int P, int G, int C, int nCh)
{
  int bg = blockIdx.x;
  if (pad[bg] <= 0.5f) return;
  int b = bg / G;
  int g = bg - b * G;
  int tid = threadIdx.x;
  int lane = tid & 63;
  int wv = tid >> 6;
  float4 gb = gtbb[bg];
  int lbl = gt_labels[bg];
  float gcx = (gb.x + gb.z) * 0.5f, gcy = (gb.y + gb.w) * 0.5f;
  size_t bP = (size_t)b * P;
  const unsigned long long* vmb = vmask + (size_t)b * nCh;
  const float4* pAB = predAB + (size_t)b * nCh;
  const unsigned B1E8 = __float_as_uint(1e8f);

  __shared__ unsigned long long bufM[NW*CAP], bufC[NW*CAP], bufI[NW*CAP];
  __shared__ uint2 sgeo[MAXCH];               // {flags: bit0 geoI, bit1 geoM; drr bits}
  __shared__ unsigned long long svm[MAXCH];   // per-chunk valid bitmask
  __shared__ unsigned int shwC, shwM, shwI;
  if (tid == 0){ shwC = 0xFFFFFFFFu; shwM = 0u; shwI = 0u; }
  // cooperative per-chunk geo precompute (bit-identical expressions to R13)
  for (int ch = tid; ch < nCh; ch += 256){
    float4 pA = pAB[ch];
    float4 rA = prAB[ch];
    float strc = strC[ch];
    bool geoI = !(pA.x < gb.z && pA.z > gb.x && pA.y < gb.w && pA.w > gb.y);
    bool geoM = !(rA.z > gb.x && rA.x < gb.z && rA.w > gb.y && rA.y < gb.w);
    float dxr = fmaxf(0.0f, fmaxf(rA.x - gcx, gcx - rA.z));
    float dyr = fmaxf(0.0f, fmaxf(rA.y - gcy, gcy - rA.w));
    float drr = sqrtf(dxr*dxr + dyr*dyr) / strc;
    sgeo[ch] = make_uint2((geoI ? 1u : 0u) | (geoM ? 2u : 0u), __float_as_uint(drr));
    svm[ch] = vmb[ch];
  }
  __syncthreads();
  unsigned long long* bM = bufM + wv*CAP;
  unsigned long long* bC = bufC + wv*CAP;
  unsigned long long* bI = bufI + wv*CAP;

  int cntM = 0, cntC = 0, cntI = 0;
  int zM = 0, zC = 0;
  unsigned long long Tm = 0ull, Tc = 0ull;
  unsigned long long Ti = 0x00000000FFFFFFFFull;    // prune iou==0 always
  unsigned cbits = 0xFFFFFFFFu, mBbits = 0u, iBb = 0u;
  float thr = 1e30f, mB = 0.0f;
  unsigned long long laneLT = (1ull << lane) - 1ull;

  int c0 = wv;
  int pf = c0 * 64 + lane;
  bool inb = (c0 < nCh) && (pf < P);
  float4 pb = inb ? pred_bboxes[bP + pf] : make_float4(0,0,0,0);
  for (int c = c0; c < nCh; c += NW){
    // unconditional register prefetch of next chunk's pred box (needed ~always)
    int cn = c + NW;
    int pn = cn * 64 + lane;
    bool inbn = (cn < nCh) && (pn < P);
    float4 pbn = make_float4(0,0,0,0);
    if (inbn) pbn = pred_bboxes[bP + pn];
    { unsigned sC = shwC; if (sC < cbits){ cbits = sC;
        thr = 3.0f + log10f(__uint_as_float(cbits) * 1.00002f + 1e-6f); } }
    { unsigned sM = shwM; if (sM > mBbits){ mBbits = sM; mB = __uint_as_float(sM); } }
    { unsigned sI = shwI; if (sI > iBb) iBb = sI; }
    uint2 ge = sgeo[c];
    bool geoI = (ge.x & 1u) != 0u;
    bool geoM = (ge.x & 2u) != 0u;
    float drr = __uint_as_float(ge.y);
    bool poolM = (zM >= TK) || (mBbits > 0u);
    bool poolC = (zC >= TK) || (cbits < B1E8);
    bool skipMt = geoM && poolM;
    bool skipCt = (drr > thr) && poolC;
    if (!(geoI && skipMt && skipCt)){
      int p = c * 64 + lane;
      float iou = iou_fn(pb, gb);
      unsigned long long keyI = ((unsigned long long)__float_as_uint(iou) << 32) | (unsigned)p;
      bool candI = inb && (keyI > Ti) && !((unsigned)(keyI >> 32) < iBb);
      if (cntI > CAP - 64){
        Ti = squeeze13(bI, cntI, lane);
        unsigned ib = (unsigned)(Ti >> 32);
        if (ib > iBb) iBb = ib;
        if (lane == 0 && ib) atomicMax(&shwI, ib);
        candI = candI && (keyI > Ti) && !((unsigned)(keyI >> 32) < iBb);
      }
      { unsigned long long mk = __ballot(candI);
        if (mk){ int off = cntI + __popcll(mk & laneLT); if (candI) bI[off] = keyI; cntI += __popcll(mk); } }
      if (!(skipMt && skipCt)){
        // ---- full path (identical to R13 body) ----
        float4 pr = inb ? priors[p] : make_float4(0,0,0,0);
        bool vb = inb && (((svm[c] >> lane) & 1ull) != 0ull);
        bool ig = inb && (pr.x > gb.x) && (pr.y > gb.y) && (gb.z > pr.x) && (gb.w > pr.y);
        bool pos = ig && (iou > 0.0f);
        float i2 = iou * iou;
        float bnd = (i2 * i2) * i2 * 1.000002f;     // >= sigmoid*powf(iou,6)
        bool needm = pos && !(bnd < mB);
        float dist = 0.0f; bool needc = false;
        if (vb){
          float dx = pr.x - gcx, dy = pr.y - gcy;
          dist = sqrtf(dx*dx + dy*dy) / pr.z;
          needc = !(dist > thr);
        }
        float sc = 0.0f;
        if (needm || needc) sc = pred_scores[(bP + p) * C + lbl];
        unsigned long long keyM = 0;
        if (__ballot(needm)){
          float met = sigmoid_f(sc) * powf(iou, 6.0f);
          if (needm)
            keyM = ((unsigned long long)__float_as_uint(met) << 32)
                 | (unsigned)~(unsigned)((p << 1) | 1);
        }
        if (zM < TK && inb && !pos)                 // zero-metric fill pool
          keyM = (unsigned long long)(unsigned)~(unsigned)((p << 1) | (ig ? 1 : 0));
        bool candM = (keyM != 0ull) && (keyM > Tm) && !((unsigned)(keyM >> 32) < mBbits);
        unsigned long long keyC = 0;
        if (zC < TK && inb && !vb)                  // invalid-cost fill pool
          keyC = ~(((unsigned long long)__float_as_uint(1e8f) << 32) | (unsigned)p);
        if (__ballot(needc)){
          float cst = cost_full(iou, sc, dist);
          if (needc)
            keyC = ~(((unsigned long long)__float_as_uint(cst) << 32) | (unsigned)p);
        }
        bool candC = (keyC != 0ull) && (keyC > Tc) && !((unsigned)((~keyC) >> 32) > cbits);
        if (cntM > CAP - 64){
          Tm = squeeze13(bM, cntM, lane);
          unsigned tb = (unsigned)(Tm >> 32);
          if (tb > mBbits){ mBbits = tb; mB = __uint_as_float(tb); }
          if (lane == 0 && tb) atomicMax(&shwM, tb);
          candM = candM && (keyM > Tm) && !((unsigned)(keyM >> 32) < mBbits);
        }
        { unsigned long long mk = __ballot(candM);
          if (mk){
            int off = cntM + __popcll(mk & laneLT);
            if (candM) bM[off] = keyM;
            cntM += __popcll(mk);
            unsigned long long zk = __ballot(candM && !pos);
            zM += __popcll(zk);
          } }
        if (cntC > CAP - 64){
          Tc = squeeze13(bC, cntC, lane);
          unsigned cb = (unsigned)((~Tc) >> 32);
          if (cb < cbits){ cbits = cb;
            thr = 3.0f + log10f(__uint_as_float(cbits) * 1.00002f + 1e-6f); }
          if (lane == 0) atomicMin(&shwC, cb);
          candC = candC && (keyC > Tc) && !((unsigned)((~keyC) >> 32) > cbits);
        }
        { unsigned long long mk = __ballot(candC);
          if (mk){
            int off = cntC + __popcll(mk & laneLT);
            if (candC) bC[off] = keyC;
            cntC += __popcll(mk);
            unsigned long long zk = __ballot(candC && !vb);
            zC += __popcll(zk);
          } }
      }
    }
    pb = pbn; inb = inbn;
  }

  squeeze13(bI, cntI, lane);
  squeeze13(bM, cntM, lane);
  squeeze13(bC, cntC, lane);
  __syncthreads();
  if (wv != 0) return;

  // ---- wave0: global top-13 from 4x13 survivors per criterion ----
  int w13 = lane / TK, r13 = lane - w13 * TK;
  int kd;
  { // iou -> dynamic_k (desc-order sum, fp-exact vs ref)
    unsigned long long e = (lane < NW*TK) ? bufI[w13*CAP + r13] : 0ull;
    float ksum = 0.0f;
    for (int r = 0; r < TK; ++r){
      unsigned long long m = e; int l = lane;
      bfly_max_u64(m, l);
      ksum += __uint_as_float((unsigned)(m >> 32));
      if (lane == l) e = 0ull;
    }
    kd = (int)ksum; if (kd < 1) kd = 1;
  }
  { // metric -> fg marks
    unsigned long long e = (lane < NW*TK) ? bufM[w13*CAP + r13] : 0ull;
    for (int r = 0; r < TK; ++r){
      unsigned long long m = e; int l = lane;
      bfly_max_u64(m, l);
      if (m == 0ull) break;
      if (lane == 0){
        unsigned ix = ~(unsigned)(m & 0xFFFFFFFFull);
        if (ix & 1u) atomicOr(&acc[bP + (ix >> 1)], 2u);
      }
      if (lane == l) e = 0ull;
    }
  }
  { // cost -> first kd selections; multi-detect on 1->2 transition
    unsigned long long e = (lane < NW*TK) ? bufC[w13*CAP + r13] : 0ull;
    for (int r = 0; r < kd; ++r){
      unsigned long long m = e; int l = lane;
      bfly_max_u64(m, l);
      if (m == 0ull) break;
      if (lane == 0){
        unsigned pp = (unsigned)((~m) & 0xFFFFFFFFull);
        unsigned old = atomicAdd(&acc[bP + pp], (1u << 17) | ((unsigned)g << 2));
        if ((old >> 17) == 1u){
          unsigned mi = atomicAdd(mcnt, 1u);
          if (mi < MCAP) mlist[mi] = (unsigned)(bP + pp);
        }
      }
      if (lane == l) e = 0ull;
    }
  }
}

// Kernel C (fused): block class 1 (x < nDecX): uniform decode — for cnt>1
// writes only weights/fg (label/bbox/metric left to class 2). Block class 2
// (x >= nDecX): sweep mlist, exact lane-parallel argmin per multi prior.
// Output fields are disjoint between classes -> no race.
__global__ __launch_bounds__(256) void k_fm(
    const float4* __restrict__ pred_bboxes, const float* __restrict__ pred_scores,
    const float4* __restrict__ priors, const int* __restrict__ gt_labels,
    const float4* __restrict__ gtb, const unsigned long long* __restrict__ vmask,
    const unsigned int* __restrict__ acc,
    const unsigned int* __restrict__ mcnt, const unsigned int* __restrict__ mlist,
    float* __restrict__ out, int B, int P, int G, int C, int nCh, int nDecX)
{
  size_t BP = (size_t)B * P;
  if ((int)blockIdx.x >= nDecX){
    // ---- multi resolution (one wave per item, strided) ----
    unsigned n = *mcnt; if (n > MCAP) n = MCAP;
    int lane = threadIdx.x & 63;
    int widx = ((int)blockIdx.y * MBX + ((int)blockIdx.x - nDecX)) * (blockDim.x >> 6)
             + ((int)threadIdx.x >> 6);
    int nw = gridDim.y * MBX * (blockDim.x >> 6);
    for (unsigned i = widx; i < n; i += nw){
      unsigned o = mlist[i];
      int b = o / P;
      int p = o - b * P;
      float4 pb = pred_bboxes[o];
      bool vld = (vmask[(size_t)b * nCh + (p >> 6)] >> (p & 63)) & 1ull;
      int mg = 0;
      if (vld){
        float4 pr = priors[p];
        const float* srow = pred_scores + (size_t)o * C;
        unsigned long long best = 0xFFFFFFFFFFFFFFFFull;
        for (int g0 = lane; g0 < G; g0 += 64){
          float4 gbx = gtb[b*G + g0];
          float iou = iou_fn(pb, gbx);
          float s = srow[gt_labels[b*G + g0]];
          float gcx = (gbx.x + gbx.z) * 0.5f, gcy = (gbx.y + gbx.w) * 0.5f;
          float dx = pr.x - gcx, dy = pr.y - gcy;
          float dist = sqrtf(dx*dx + dy*dy) / pr.z;
          float cc = cost_full(iou, s, dist);
          unsigned long long k = ((unsigned long long)__float_as_uint(cc) << 32) | (unsigned)g0;
          if (k < best) best = k;
        }
        #pragma unroll
        for (int off = 32; off >= 1; off >>= 1){
          unsigned long long ov = __shfl_xor(best, off);
          if (ov < best) best = ov;
        }
        mg = (int)(best & 0xFFFFFFFFull);
      }
      if (lane == 0){
        float4 gbx = gtb[b*G + mg];
        out[o] = (float)gt_labels[b*G + mg];
        ((float4*)(out + 2*BP))[o] = gbx;
        out[6*BP + o] = iou_fn(pb, gbx);
      }
    }
    return;
  }
  // ---- uniform decode ----
  int b = blockIdx.y;
  int p = blockIdx.x * 256 + threadIdx.x;
  __shared__ float4 sg[MAXG];
  __shared__ int sl[MAXG];
  for (int i = threadIdx.x; i < G; i += 256){
    sg[i] = gtb[b*G + i]; sl[i] = gt_labels[b*G + i];
  }
  __syncthreads();
  if (p >= P) return;
  size_t o = (size_t)b * P + p;
  unsigned int w = acc[o];
  int cnt = (int)(w >> 17);
  out[BP + o] = 1.0f;                              // weights
  out[7*BP + o] = ((w >> 1) & 1u) ? 1.0f : 0.0f;   // fg_mask_pre_prior
  if (cnt > 1) return;                             // class 2 writes the rest
  bool fg = cnt > 0;
  int mg = fg ? (int)((w >> 2) & 0x7FFFu) : 0;
  float4 pb = pred_bboxes[o];
  out[o] = fg ? (float)sl[mg] : 80.0f;
  float4 ob = fg ? sg[mg] : make_float4(0.f, 0.f, 0.f, 0.f);
  ((float4*)(out + 2*BP))[o] = ob;
  out[6*BP + o] = fg ? iou_fn(pb, sg[mg]) : 0.0f;
}

extern "C" void kernel_launch(void* const* d_in, const int* in_sizes, int n_in,
                              void* d_out, int out_size, void* d_ws, size_t ws_size,
                              hipStream_t stream)
{
  const float4* pred_bboxes = (const float4*)d_in[0];
  const float*  pred_scores = (const float*)d_in[1];
  const float4* priors      = (const float4*)d_in[2];
  const int*    gt_labels   = (const int*)d_in[3];
  const float4* gt_bboxes   = (const float4*)d_in[4];
  const float*  pad         = (const float*)d_in[5];
  int P = in_sizes[2] / 4;                 // 8400
  int B = in_sizes[0] / (P * 4);           // 16
  int C = in_sizes[1] / (B * P);           // 80
  int G = in_sizes[4] / (B * 4);           // 100
  int BG = B * G;
  int nCh = (P + 63) >> 6;                 // 132 (<= MAXCH)

  uint8_t* ws = (uint8_t*)d_ws;
  size_t off = 0;
  unsigned long long* vmask = (unsigned long long*)(ws + off); off += (size_t)B * nCh * 8;
  unsigned int* acc = (unsigned int*)(ws + off);               off += (size_t)B * P * 4;
  off = (off + 15) & ~(size_t)15;
  unsigned int* mcnt = (unsigned int*)(ws + off);              off += 16;
  unsigned int* mlist = (unsigned int*)(ws + off);             off += (size_t)MCAP * 4;
  off = (off + 15) & ~(size_t)15;
  float4* predAB = (float4*)(ws + off);                        off += (size_t)B * nCh * 16;
  float4* prAB = (float4*)(ws + off);                          off += (size_t)nCh * 16;
  float* strC = (float*)(ws + off);                            off += (size_t)nCh * 4;
  float* out = (float*)d_out;

  int nDecX = (P + 255) / 256;
  dim3 gridA(nDecX, B);
  dim3 gridF(nDecX + MBX, B);
  k_valid<<<gridA, 256, 0, stream>>>(priors, pred_bboxes, gt_bboxes, pad,
                                     vmask, acc, mcnt, predAB, prAB, strC, P, G, nCh);
  k_scan<<<BG, NW*64, 0, stream>>>(pred_bboxes, pred_scores, priors, gt_labels,
                                   gt_bboxes, pad, vmask, predAB, prAB, strC,
                                   acc, mcnt, mlist, P, G, C, nCh);
  k_fm<<<gridF, 256, 0, stream>>>(pred_bboxes, pred_scores, priors, gt_labels,
                                  gt_bboxes, vmask, acc, mcnt, mlist, out,
                                  B, P, G, C, nCh, nDecX);
}

// Round 16
// 255.406 us; speedup vs baseline: 1.0708x; 1.0280x over previous
//
#include <hip/hip_runtime.h>
#include <cstdint>
#include <climits>
#include <cstddef>

#define TK 13
#define MAXG 128
#define CAP 192
#define NW 4
#define MCAP 24576
#define MAXCH 160
#define MBX 8

__device__ __forceinline__ float iou_fn(const float4 pb, const float4 gb){
  float pa = (pb.z - pb.x) * (pb.w - pb.y);
  float ga = (gb.z - gb.x) * (gb.w - gb.y);
  float ltx = fmaxf(pb.x, gb.x), lty = fmaxf(pb.y, gb.y);
  float rbx = fminf(pb.z, gb.z), rby = fminf(pb.w, gb.w);
  float w = fmaxf(rbx - ltx, 0.0f), h = fmaxf(rby - lty, 0.0f);
  float inter = w * h;
  float uni = pa + ga - inter;
  return inter / fmaxf(uni, 1e-6f);
}

__device__ __forceinline__ float sigmoid_f(float x){ return 1.0f / (1.0f + expf(-x)); }

// Same expression order as R0-R15 (passed absmax 0) — do not alter.
__device__ __forceinline__ float cost_full(float iou, float s, float dist){
  float sig = sigmoid_f(s);
  float iouc = -logf(iou + 1e-7f) * 3.0f;
  float scale = iou - sig;
  float bce = fmaxf(s, 0.0f) + log1pf(expf(-fabsf(s))) - s * iou;
  float cls = bce * scale * scale;
  float soft = powf(10.0f, dist - 3.0f);
  return cls + iouc + soft;
}

__device__ __forceinline__ void bfly_max_u64(unsigned long long &v, int &l){
  #pragma unroll
  for (int off = 32; off >= 1; off >>= 1){
    unsigned long long ov = __shfl_xor(v, off);
    int ol = __shfl_xor(l, off);
    if (ov > v){ v = ov; l = ol; }
  }
}

// wave-level: find 13th-largest of cnt entries in buf; compact top-13 to
// buf[0..12]; return 13th key (0 if fewer than 13 nonzero). Keys unique.
__device__ __forceinline__ unsigned long long squeeze13(unsigned long long* buf, int& cnt, int lane){
  unsigned long long e0 = (lane < cnt) ? buf[lane] : 0ull;
  unsigned long long e1 = (lane + 64 < cnt) ? buf[lane + 64] : 0ull;
  unsigned long long e2 = (lane + 128 < cnt) ? buf[lane + 128] : 0ull;
  if (e0 < e2){ unsigned long long t = e0; e0 = e2; e2 = t; }
  if (e0 < e1){ unsigned long long t = e0; e0 = e1; e1 = t; }
  if (e1 < e2){ unsigned long long t = e1; e1 = e2; e2 = t; }
  unsigned long long T = 0;
  for (int r = 0; r < TK; ++r){
    unsigned long long m = e0; int l = lane;
    bfly_max_u64(m, l);
    if (lane == 0) buf[r] = m;
    T = m;
    if (lane == l){ e0 = e1; e1 = e2; e2 = 0ull; }
  }
  cnt = TK;
  return T;
}

// Kernel A: valid bitmask + acc init + mcnt zero + per-chunk AABBs.
__global__ __launch_bounds__(256) void k_valid(
    const float4* __restrict__ priors, const float4* __restrict__ pred_bboxes,
    const float4* __restrict__ gtb, const float* __restrict__ pad,
    unsigned long long* __restrict__ vmask, unsigned int* __restrict__ acc,
    unsigned int* __restrict__ mcnt,
    float4* __restrict__ predAB, float4* __restrict__ prAB, float* __restrict__ strC,
    int P, int G, int nCh)
{
  int b = blockIdx.y;
  int p = blockIdx.x * 256 + threadIdx.x;
  if (b == 0 && p == 0) *mcnt = 0u;
  __shared__ float4 sg[MAXG];
  __shared__ float sp[MAXG];
  for (int i = threadIdx.x; i < G; i += 256){ sg[i] = gtb[b*G + i]; sp[i] = pad[b*G + i]; }
  __syncthreads();
  int lane = threadIdx.x & 63;
  int ch = p >> 6;
  bool inb = p < P;
  float4 pr = inb ? priors[p] : make_float4(0,0,0,0);
  float4 pb = inb ? pred_bboxes[(size_t)b*P + p] : make_float4(0,0,0,0);
  bool v = false;
  if (inb){
    #pragma unroll 4
    for (int g = 0; g < G; ++g){
      float4 gb = sg[g];
      bool ig = (pr.x > gb.x) && (pr.y > gb.y) && (gb.z > pr.x) && (gb.w > pr.y);
      v = v || (ig && sp[g] > 0.5f);
    }
    acc[(size_t)b * P + p] = 0u;
  }
  unsigned long long m = __ballot(v);
  if (lane == 0 && ch < nCh) vmask[(size_t)b * nCh + ch] = m;
  float inf = __builtin_inff();
  float x1 = inb ? pb.x : inf,  y1 = inb ? pb.y : inf;
  float x2 = inb ? pb.z : -inf, y2 = inb ? pb.w : -inf;
  float px1 = inb ? pr.x : inf,  py1 = inb ? pr.y : inf;
  float px2 = inb ? pr.x : -inf, py2 = inb ? pr.y : -inf;
  #pragma unroll
  for (int off = 32; off >= 1; off >>= 1){
    x1 = fminf(x1, __shfl_xor(x1, off));  y1 = fminf(y1, __shfl_xor(y1, off));
    x2 = fmaxf(x2, __shfl_xor(x2, off));  y2 = fmaxf(y2, __shfl_xor(y2, off));
    px1 = fminf(px1, __shfl_xor(px1, off)); py1 = fminf(py1, __shfl_xor(py1, off));
    px2 = fmaxf(px2, __shfl_xor(px2, off)); py2 = fmaxf(py2, __shfl_xor(py2, off));
  }
  if (lane == 0 && ch < nCh){
    predAB[(size_t)b * nCh + ch] = make_float4(x1, y1, x2, y2);
    if (b == 0){ prAB[ch] = make_float4(px1, py1, px2, py2); strC[ch] = pr.z; }
  }
}

// Kernel B: one 4-wave block per (b,g). Chunk-PAIR iteration per wave
// (halved fixed overhead, 2 prefetched loads in flight); per-chunk body is
// R15's verbatim; ascending-p order preserved (fill-pool soundness).
__global__ __launch_bounds__(256) void k_scan(
    const float4* __restrict__ pred_bboxes, const float* __restrict__ pred_scores,
    const float4* __restrict__ priors, const int* __restrict__ gt_labels,
    const float4* __restrict__ gtbb, const float* __restrict__ pad,
    const unsigned long long* __restrict__ vmask,
    const float4* __restrict__ predAB, const float4* __restrict__ prAB,
    const float* __restrict__ strC,
    unsigned int* __restrict__ acc, unsigned int* __restrict__ mcnt,
    unsigned int* __restrict__ mlist,
    int P, int G, int C, int nCh)
{
  int bg = blockIdx.x;
  if (pad[bg] <= 0.5f) return;
  int b = bg / G;
  int g = bg - b * G;
  int tid = threadIdx.x;
  int lane = tid & 63;
  int wv = tid >> 6;
  float4 gb = gtbb[bg];
  int lbl = gt_labels[bg];
  float gcx = (gb.x + gb.z) * 0.5f, gcy = (gb.y + gb.w) * 0.5f;
  size_t bP = (size_t)b * P;
  const unsigned long long* vmb = vmask + (size_t)b * nCh;
  const float4* pAB = predAB + (size_t)b * nCh;
  const unsigned B1E8 = __float_as_uint(1e8f);

  __shared__ unsigned long long bufM[NW*CAP], bufC[NW*CAP], bufI[NW*CAP];
  __shared__ uint2 sgeo[MAXCH];               // {flags: bit0 geoI, bit1 geoM; drr bits}
  __shared__ unsigned long long svm[MAXCH];   // per-chunk valid bitmask
  __shared__ unsigned int shwC, shwM, shwI;
  if (tid == 0){ shwC = 0xFFFFFFFFu; shwM = 0u; shwI = 0u; }
  // cooperative per-chunk geo precompute (bit-identical expressions to R13)
  for (int ch = tid; ch < nCh; ch += 256){
    float4 pA = pAB[ch];
    float4 rA = prAB[ch];
    float strc = strC[ch];
    bool geoI = !(pA.x < gb.z && pA.z > gb.x && pA.y < gb.w && pA.w > gb.y);
    bool geoM = !(rA.z > gb.x && rA.x < gb.z && rA.w > gb.y && rA.y < gb.w);
    float dxr = fmaxf(0.0f, fmaxf(rA.x - gcx, gcx - rA.z));
    float dyr = fmaxf(0.0f, fmaxf(rA.y - gcy, gcy - rA.w));
    float drr = sqrtf(dxr*dxr + dyr*dyr) / strc;
    sgeo[ch] = make_uint2((geoI ? 1u : 0u) | (geoM ? 2u : 0u), __float_as_uint(drr));
    svm[ch] = vmb[ch];
  }
  __syncthreads();
  unsigned long long* bM = bufM + wv*CAP;
  unsigned long long* bC = bufC + wv*CAP;
  unsigned long long* bI = bufI + wv*CAP;

  int cntM = 0, cntC = 0, cntI = 0;
  int zM = 0, zC = 0;
  unsigned long long Tm = 0ull, Tc = 0ull;
  unsigned long long Ti = 0x00000000FFFFFFFFull;    // prune iou==0 always
  unsigned cbits = 0xFFFFFFFFu, mBbits = 0u, iBb = 0u;
  float thr = 1e30f, mB = 0.0f;
  unsigned long long laneLT = (1ull << lane) - 1ull;

  // per-chunk body (R15 verbatim; pushes in call order = ascending p)
  auto body = [&](int c, float4 pb, bool inb){
    uint2 ge = sgeo[c];
    bool geoI = (ge.x & 1u) != 0u;
    bool geoM = (ge.x & 2u) != 0u;
    float drr = __uint_as_float(ge.y);
    bool poolM = (zM >= TK) || (mBbits > 0u);
    bool poolC = (zC >= TK) || (cbits < B1E8);
    bool skipMt = geoM && poolM;
    bool skipCt = (drr > thr) && poolC;
    if (geoI && skipMt && skipCt) return;
    int p = c * 64 + lane;
    float iou = iou_fn(pb, gb);
    unsigned long long keyI = ((unsigned long long)__float_as_uint(iou) << 32) | (unsigned)p;
    bool candI = inb && (keyI > Ti) && !((unsigned)(keyI >> 32) < iBb);
    if (cntI > CAP - 64){
      Ti = squeeze13(bI, cntI, lane);
      unsigned ib = (unsigned)(Ti >> 32);
      if (ib > iBb) iBb = ib;
      if (lane == 0 && ib) atomicMax(&shwI, ib);
      candI = candI && (keyI > Ti) && !((unsigned)(keyI >> 32) < iBb);
    }
    { unsigned long long mk = __ballot(candI);
      if (mk){ int off = cntI + __popcll(mk & laneLT); if (candI) bI[off] = keyI; cntI += __popcll(mk); } }
    if (skipMt && skipCt) return;
    // ---- full path ----
    float4 pr = inb ? priors[p] : make_float4(0,0,0,0);
    bool vb = inb && (((svm[c] >> lane) & 1ull) != 0ull);
    bool ig = inb && (pr.x > gb.x) && (pr.y > gb.y) && (gb.z > pr.x) && (gb.w > pr.y);
    bool pos = ig && (iou > 0.0f);
    float i2 = iou * iou;
    float bnd = (i2 * i2) * i2 * 1.000002f;     // >= sigmoid*powf(iou,6)
    bool needm = pos && !(bnd < mB);
    float dist = 0.0f; bool needc = false;
    if (vb){
      float dx = pr.x - gcx, dy = pr.y - gcy;
      dist = sqrtf(dx*dx + dy*dy) / pr.z;
      needc = !(dist > thr);
    }
    float sc = 0.0f;
    if (needm || needc) sc = pred_scores[(bP + p) * C + lbl];
    unsigned long long keyM = 0;
    if (__ballot(needm)){
      float met = sigmoid_f(sc) * powf(iou, 6.0f);
      if (needm)
        keyM = ((unsigned long long)__float_as_uint(met) << 32)
             | (unsigned)~(unsigned)((p << 1) | 1);
    }
    if (zM < TK && inb && !pos)                 // zero-metric fill pool
      keyM = (unsigned long long)(unsigned)~(unsigned)((p << 1) | (ig ? 1 : 0));
    bool candM = (keyM != 0ull) && (keyM > Tm) && !((unsigned)(keyM >> 32) < mBbits);
    unsigned long long keyC = 0;
    if (zC < TK && inb && !vb)                  // invalid-cost fill pool
      keyC = ~(((unsigned long long)__float_as_uint(1e8f) << 32) | (unsigned)p);
    if (__ballot(needc)){
      float cst = cost_full(iou, sc, dist);
      if (needc)
        keyC = ~(((unsigned long long)__float_as_uint(cst) << 32) | (unsigned)p);
    }
    bool candC = (keyC != 0ull) && (keyC > Tc) && !((unsigned)((~keyC) >> 32) > cbits);
    if (cntM > CAP - 64){
      Tm = squeeze13(bM, cntM, lane);
      unsigned tb = (unsigned)(Tm >> 32);
      if (tb > mBbits){ mBbits = tb; mB = __uint_as_float(tb); }
      if (lane == 0 && tb) atomicMax(&shwM, tb);
      candM = candM && (keyM > Tm) && !((unsigned)(keyM >> 32) < mBbits);
    }
    { unsigned long long mk = __ballot(candM);
      if (mk){
        int off = cntM + __popcll(mk & laneLT);
        if (candM) bM[off] = keyM;
        cntM += __popcll(mk);
        unsigned long long zk = __ballot(candM && !pos);
        zM += __popcll(zk);
      } }
    if (cntC > CAP - 64){
      Tc = squeeze13(bC, cntC, lane);
      unsigned cb = (unsigned)((~Tc) >> 32);
      if (cb < cbits){ cbits = cb;
        thr = 3.0f + log10f(__uint_as_float(cbits) * 1.00002f + 1e-6f); }
      if (lane == 0) atomicMin(&shwC, cb);
      candC = candC && (keyC > Tc) && !((unsigned)((~keyC) >> 32) > cbits);
    }
    { unsigned long long mk = __ballot(candC);
      if (mk){
        int off = cntC + __popcll(mk & laneLT);
        if (candC) bC[off] = keyC;
        cntC += __popcll(mk);
        unsigned long long zk = __ballot(candC && !vb);
        zC += __popcll(zk);
      } }
  };

  // pair loop: wave wv handles chunks {2wv, 2wv+1, 2wv+2NW, 2wv+2NW+1, ...}
  int base = 2 * wv;
  float4 pb0 = make_float4(0,0,0,0), pb1 = pb0;
  bool in0 = false, in1 = false;
  if (base < nCh){
    int q0 = base * 64 + lane;
    if (q0 < P){ in0 = true; pb0 = pred_bboxes[bP + q0]; }
    int q1 = (base + 1) * 64 + lane;
    if (base + 1 < nCh && q1 < P){ in1 = true; pb1 = pred_bboxes[bP + q1]; }
  }
  for (; base < nCh; base += 2 * NW){
    // prefetch next pair
    int nb = base + 2 * NW;
    float4 pn0 = make_float4(0,0,0,0), pn1 = pn0;
    bool inn0 = false, inn1 = false;
    if (nb < nCh){
      int q0 = nb * 64 + lane;
      if (q0 < P){ inn0 = true; pn0 = pred_bboxes[bP + q0]; }
      int q1 = (nb + 1) * 64 + lane;
      if (nb + 1 < nCh && q1 < P){ inn1 = true; pn1 = pred_bboxes[bP + q1]; }
    }
    // refresh shared bounds once per pair
    { unsigned sC = shwC; if (sC < cbits){ cbits = sC;
        thr = 3.0f + log10f(__uint_as_float(cbits) * 1.00002f + 1e-6f); } }
    { unsigned sM = shwM; if (sM > mBbits){ mBbits = sM; mB = __uint_as_float(sM); } }
    { unsigned sI = shwI; if (sI > iBb) iBb = sI; }
    body(base, pb0, in0);
    if (base + 1 < nCh) body(base + 1, pb1, in1);
    pb0 = pn0; pb1 = pn1; in0 = inn0; in1 = inn1;
  }

  squeeze13(bI, cntI, lane);
  squeeze13(bM, cntM, lane);
  squeeze13(bC, cntC, lane);
  __syncthreads();
  if (wv != 0) return;

  // ---- wave0: global top-13 from 4x13 survivors per criterion ----
  int w13 = lane / TK, r13 = lane - w13 * TK;
  int kd;
  { // iou -> dynamic_k (desc-order sum, fp-exact vs ref)
    unsigned long long e = (lane < NW*TK) ? bufI[w13*CAP + r13] : 0ull;
    float ksum = 0.0f;
    for (int r = 0; r < TK; ++r){
      unsigned long long m = e; int l = lane;
      bfly_max_u64(m, l);
      ksum += __uint_as_float((unsigned)(m >> 32));
      if (lane == l) e = 0ull;
    }
    kd = (int)ksum; if (kd < 1) kd = 1;
  }
  { // metric -> fg marks
    unsigned long long e = (lane < NW*TK) ? bufM[w13*CAP + r13] : 0ull;
    for (int r = 0; r < TK; ++r){
      unsigned long long m = e; int l = lane;
      bfly_max_u64(m, l);
      if (m == 0ull) break;
      if (lane == 0){
        unsigned ix = ~(unsigned)(m & 0xFFFFFFFFull);
        if (ix & 1u) atomicOr(&acc[bP + (ix >> 1)], 2u);
      }
      if (lane == l) e = 0ull;
    }
  }
  { // cost -> first kd selections; multi-detect on 1->2 transition
    unsigned long long e = (lane < NW*TK) ? bufC[w13*CAP + r13] : 0ull;
    for (int r = 0; r < kd; ++r){
      unsigned long long m = e; int l = lane;
      bfly_max_u64(m, l);
      if (m == 0ull) break;
      if (lane == 0){
        unsigned pp = (unsigned)((~m) & 0xFFFFFFFFull);
        unsigned old = atomicAdd(&acc[bP + pp], (1u << 17) | ((unsigned)g << 2));
        if ((old >> 17) == 1u){
          unsigned mi = atomicAdd(mcnt, 1u);
          if (mi < MCAP) mlist[mi] = (unsigned)(bP + pp);
        }
      }
      if (lane == l) e = 0ull;
    }
  }
}

// Kernel C (fused): block class 1 (x < nDecX): uniform decode — for cnt>1
// writes only weights/fg. Block class 2 (x >= nDecX): sweep mlist, exact
// lane-parallel argmin per multi prior. Disjoint output fields -> no race.
__global__ __launch_bounds__(256) void k_fm(
    const float4* __restrict__ pred_bboxes, const float* __restrict__ pred_scores,
    const float4* __restrict__ priors, const int* __restrict__ gt_labels,
    const float4* __restrict__ gtb, const unsigned long long* __restrict__ vmask,
    const unsigned int* __restrict__ acc,
    const unsigned int* __restrict__ mcnt, const unsigned int* __restrict__ mlist,
    float* __restrict__ out, int B, int P, int G, int C, int nCh, int nDecX)
{
  size_t BP = (size_t)B * P;
  if ((int)blockIdx.x >= nDecX){
    // ---- multi resolution (one wave per item, strided) ----
    unsigned n = *mcnt; if (n > MCAP) n = MCAP;
    int lane = threadIdx.x & 63;
    int widx = ((int)blockIdx.y * MBX + ((int)blockIdx.x - nDecX)) * (blockDim.x >> 6)
             + ((int)threadIdx.x >> 6);
    int nw = gridDim.y * MBX * (blockDim.x >> 6);
    for (unsigned i = widx; i < n; i += nw){
      unsigned o = mlist[i];
      int b = o / P;
      int p = o - b * P;
      float4 pb = pred_bboxes[o];
      bool vld = (vmask[(size_t)b * nCh + (p >> 6)] >> (p & 63)) & 1ull;
      int mg = 0;
      if (vld){
        float4 pr = priors[p];
        const float* srow = pred_scores + (size_t)o * C;
        unsigned long long best = 0xFFFFFFFFFFFFFFFFull;
        for (int g0 = lane; g0 < G; g0 += 64){
          float4 gbx = gtb[b*G + g0];
          float iou = iou_fn(pb, gbx);
          float s = srow[gt_labels[b*G + g0]];
          float gcx = (gbx.x + gbx.z) * 0.5f, gcy = (gbx.y + gbx.w) * 0.5f;
          float dx = pr.x - gcx, dy = pr.y - gcy;
          float dist = sqrtf(dx*dx + dy*dy) / pr.z;
          float cc = cost_full(iou, s, dist);
          unsigned long long k = ((unsigned long long)__float_as_uint(cc) << 32) | (unsigned)g0;
          if (k < best) best = k;
        }
        #pragma unroll
        for (int off = 32; off >= 1; off >>= 1){
          unsigned long long ov = __shfl_xor(best, off);
          if (ov < best) best = ov;
        }
        mg = (int)(best & 0xFFFFFFFFull);
      }
      if (lane == 0){
        float4 gbx = gtb[b*G + mg];
        out[o] = (float)gt_labels[b*G + mg];
        ((float4*)(out + 2*BP))[o] = gbx;
        out[6*BP + o] = iou_fn(pb, gbx);
      }
    }
    return;
  }
  // ---- uniform decode ----
  int b = blockIdx.y;
  int p = blockIdx.x * 256 + threadIdx.x;
  __shared__ float4 sg[MAXG];
  __shared__ int sl[MAXG];
  for (int i = threadIdx.x; i < G; i += 256){
    sg[i] = gtb[b*G + i]; sl[i] = gt_labels[b*G + i];
  }
  __syncthreads();
  if (p >= P) return;
  size_t o = (size_t)b * P + p;
  unsigned int w = acc[o];
  int cnt = (int)(w >> 17);
  out[BP + o] = 1.0f;                              // weights
  out[7*BP + o] = ((w >> 1) & 1u) ? 1.0f : 0.0f;   // fg_mask_pre_prior
  if (cnt > 1) return;                             // class 2 writes the rest
  bool fg = cnt > 0;
  int mg = fg ? (int)((w >> 2) & 0x7FFFu) : 0;
  float4 pb = pred_bboxes[o];
  out[o] = fg ? (float)sl[mg] : 80.0f;
  float4 ob = fg ? sg[mg] : make_float4(0.f, 0.f, 0.f, 0.f);
  ((float4*)(out + 2*BP))[o] = ob;
  out[6*BP + o] = fg ? iou_fn(pb, sg[mg]) : 0.0f;
}

extern "C" void kernel_launch(void* const* d_in, const int* in_sizes, int n_in,
                              void* d_out, int out_size, void* d_ws, size_t ws_size,
                              hipStream_t stream)
{
  const float4* pred_bboxes = (const float4*)d_in[0];
  const float*  pred_scores = (const float*)d_in[1];
  const float4* priors      = (const float4*)d_in[2];
  const int*    gt_labels   = (const int*)d_in[3];
  const float4* gt_bboxes   = (const float4*)d_in[4];
  const float*  pad         = (const float*)d_in[5];
  int P = in_sizes[2] / 4;                 // 8400
  int B = in_sizes[0] / (P * 4);           // 16
  int C = in_sizes[1] / (B * P);           // 80
  int G = in_sizes[4] / (B * 4);           // 100
  int BG = B * G;
  int nCh = (P + 63) >> 6;                 // 132 (<= MAXCH)

  uint8_t* ws = (uint8_t*)d_ws;
  size_t off = 0;
  unsigned long long* vmask = (unsigned long long*)(ws + off); off += (size_t)B * nCh * 8;
  unsigned int* acc = (unsigned int*)(ws + off);               off += (size_t)B * P * 4;
  off = (off + 15) & ~(size_t)15;
  unsigned int* mcnt = (unsigned int*)(ws + off);              off += 16;
  unsigned int* mlist = (unsigned int*)(ws + off);             off += (size_t)MCAP * 4;
  off = (off + 15) & ~(size_t)15;
  float4* predAB = (float4*)(ws + off);                        off += (size_t)B * nCh * 16;
  float4* prAB = (float4*)(ws + off);                          off += (size_t)nCh * 16;
  float* strC = (float*)(ws + off);                            off += (size_t)nCh * 4;
  float* out = (float*)d_out;

  int nDecX = (P + 255) / 256;
  dim3 gridA(nDecX, B);
  dim3 gridF(nDecX + MBX, B);
  k_valid<<<gridA, 256, 0, stream>>>(priors, pred_bboxes, gt_bboxes, pad,
                                     vmask, acc, mcnt, predAB, prAB, strC, P, G, nCh);
  k_scan<<<BG, NW*64, 0, stream>>>(pred_bboxes, pred_scores, priors, gt_labels,
                                   gt_bboxes, pad, vmask, predAB, prAB, strC,
                                   acc, mcnt, mlist, P, G, C, nCh);
  k_fm<<<gridF, 256, 0, stream>>>(pred_bboxes, pred_scores, priors, gt_labels,
                                  gt_bboxes, vmask, acc, mcnt, mlist, out,
                                  B, P, G, C, nCh, nDecX);
}